// Round 15
// baseline (157.786 us; speedup 1.0000x reference)
//
#include <hip/hip_runtime.h>
#include <stdint.h>

#define NPTS 4096
#define KNB  32
#define NCH  64
#define EPS  1e-5f
#define SLOPE 0.2f
#define MCNT 1048576.0f   // B*N*K = 8*4096*32
#define GMARG 1e-3f       // conservative survivor-gate margin (>> 2*fp32 err of e)

typedef __attribute__((ext_vector_type(4))) float f32x4;
typedef __attribute__((ext_vector_type(8))) __bf16 bf16x8;

__device__ __forceinline__ float bflo(uint32_t u) { return __uint_as_float(u << 16); }
__device__ __forceinline__ float bfhi(uint32_t u) { return __uint_as_float(u & 0xffff0000u); }
__device__ __forceinline__ uint32_t bfbits(float v) {
    return (uint32_t)__builtin_bit_cast(uint16_t, (__bf16)v);
}

// ---------- in-register bitonic sort, 64 f32 (one per lane), descending ----------
__device__ __forceinline__ float sortf_desc(float v, int lane) {
    #pragma unroll
    for (int k = 2; k <= 64; k <<= 1) {
        #pragma unroll
        for (int j = k >> 1; j > 0; j >>= 1) {
            const float o = __shfl_xor(v, j);
            const bool up = ((lane & k) == 0) == ((lane & j) == 0);
            const float mx = fmaxf(v, o), mn = fminf(v, o);
            v = up ? mx : mn;
        }
    }
    return v;
}

// ---------- top-32 set of 64 u64 keys: 15-stage half-sorts + bitonic split ----------
__device__ __forceinline__ uint64_t top32_split(uint64_t v, int lane) {
    #pragma unroll
    for (int k = 2; k <= 32; k <<= 1) {
        #pragma unroll
        for (int j = k >> 1; j > 0; j >>= 1) {
            const uint64_t o = __shfl_xor((unsigned long long)v, j);
            const bool dirDesc = ((lane & k) == 0);
            const bool lower   = ((lane & j) == 0);
            const uint64_t mx = v > o ? v : o;
            const uint64_t mn = v > o ? o : v;
            v = (dirDesc == lower) ? mx : mn;
        }
    }
    const uint64_t o = __shfl_xor((unsigned long long)v, 32);
    return v > o ? v : o;
}

// ---------- serial-insertion fallback (exact R4 d-ordering; xs.w = 0.5*|p|^2) ----------
__device__ __noinline__ uint32_t knn_row_serial(const float4* xs, int n, int lane) {
    const float4 ctr = xs[n];
    const float cw2 = ctr.w + ctr.w;            // exact |c|^2
    uint32_t lh = 0u, ll = 0u;
    uint64_t tau = 0ull;
    for (int c = 0; c < 64; ++c) {
        const int m = (c << 6) + lane;
        const float4 p = xs[m];
        const float inner = fmaf(p.z, ctr.z, fmaf(p.y, ctr.y, p.x * ctr.x));
        const float d = fmaf(2.0f, inner, -cw2) - (p.w + p.w);
        const uint32_t u  = __float_as_uint(d);
        const uint32_t kh = u ^ (uint32_t)(((int32_t)u >> 31) | 0x80000000);
        const uint32_t kl = ~(uint32_t)m;
        const uint64_t key = ((uint64_t)kh << 32) | kl;
        uint64_t cand = __ballot(key > tau);
        while (cand) {
            const int src = __ffsll((unsigned long long)cand) - 1;
            cand &= cand - 1;
            const uint32_t ch  = __shfl(kh, src);
            const uint32_t cl2 = __shfl(kl, src);
            const uint64_t ck = ((uint64_t)ch << 32) | cl2;
            if (ck <= tau) continue;
            const uint64_t lk = ((uint64_t)lh << 32) | ll;
            const bool take = lk < ck;
            const uint64_t tb = __ballot(take);
            const int pos = __ffsll((unsigned long long)tb) - 1;
            const uint32_t sh = __shfl_up(lh, 1);
            const uint32_t sl = __shfl_up(ll, 1);
            if (take) { lh = sh; ll = sl; }
            if (lane == pos) { lh = ch; ll = cl2; }
            tau = ((uint64_t)__shfl(lh, 31) << 32) | __shfl(ll, 31);
        }
    }
    return ~ll;
}

// ---------------- K1: exact kNN (e-gate + exact-d select) + conv1 BN stats ----------------
// R10 structure; launch_bounds WITHOUT arg2: compiler free to allocate its natural
// ~36-52 VGPR (R12 evidence) -> no spill; HW grants 8 waves/SIMD at <=64 VGPR (m69),
// avoiding the arg2 occupancy cap discovered in R11/R12.
__global__ __launch_bounds__(1024) void knn_kernel(const float* __restrict__ x,
                                                   const float* __restrict__ W1,
                                                   int* __restrict__ idx_out,
                                                   float* __restrict__ stats) {
    const int b  = blockIdx.x >> 6;
    const int n0 = (blockIdx.x & 63) * 64;
    __shared__ float4 xs[NPTS];                 // 64 KB; .w = 0.5*|p|^2
    __shared__ uint32_t surv[16][4][64];        // 16 KB (aliased as `red` at the end)
    const float* xb = x + (size_t)b * 3 * NPTS;
    for (int m = threadIdx.x; m < NPTS; m += 1024) {
        float v0 = xb[m], v1 = xb[NPTS + m], v2 = xb[2 * NPTS + m];
        xs[m] = make_float4(v0, v1, v2, 0.5f * fmaf(v2, v2, fmaf(v1, v1, v0 * v0)));
    }
    __syncthreads();
    const int wave = threadIdx.x >> 6;
    const int lane = threadIdx.x & 63;
    // per-lane conv1 weights (lane = channel)
    const float w1b0 = W1[lane * 6 + 3], w1b1 = W1[lane * 6 + 4], w1b2 = W1[lane * 6 + 5];
    const float w1a0 = W1[lane * 6 + 0] - w1b0;
    const float w1a1 = W1[lane * 6 + 1] - w1b1;
    const float w1a2 = W1[lane * 6 + 2] - w1b2;
    // moment accumulators
    float Sc0 = 0, Sc1 = 0, Sc2 = 0;
    float Scc00 = 0, Scc01 = 0, Scc02 = 0, Scc11 = 0, Scc12 = 0, Scc22 = 0;
    float Sp0 = 0, Sp1 = 0, Sp2 = 0;
    float Spp00 = 0, Spp01 = 0, Spp02 = 0, Spp11 = 0, Spp12 = 0, Spp22 = 0;
    float Scp00 = 0, Scp01 = 0, Scp02 = 0, Scp10 = 0, Scp11 = 0, Scp12 = 0,
          Scp20 = 0, Scp21 = 0, Scp22 = 0;

    const int nbase = n0 + wave * 4;
    float4 ctr[4];
    float lmax[4];
    #pragma unroll
    for (int rr = 0; rr < 4; ++rr) { ctr[rr] = xs[nbase + rr]; lmax[rr] = -3.0e38f; }
    // ---- pass A: per-lane max of e = p.c - 0.5|p|^2 (cheap gate metric) ----
    #pragma unroll 4
    for (int c = 0; c < 64; ++c) {
        const float4 p = xs[(c << 6) + lane];
        #pragma unroll
        for (int rr = 0; rr < 4; ++rr) {
            const float e = fmaf(p.z, ctr[rr].z, fmaf(p.y, ctr[rr].y, fmaf(p.x, ctr[rr].x, -p.w)));
            lmax[rr] = fmaxf(lmax[rr], e);
        }
    }
    // ---- threshold = 32nd largest lane-max, minus conservative margin ----
    float thr[4];
    #pragma unroll
    for (int rr = 0; rr < 4; ++rr)
        thr[rr] = __shfl(sortf_desc(lmax[rr], lane), 31) - GMARG;
    // ---- pass B: compact survivor indices (gate in e-metric, superset of top-32) ----
    int base[4] = {0, 0, 0, 0};
    #pragma unroll 2
    for (int c = 0; c < 64; ++c) {
        const int m = (c << 6) + lane;
        const float4 p = xs[m];
        #pragma unroll
        for (int rr = 0; rr < 4; ++rr) {
            const float e = fmaf(p.z, ctr[rr].z, fmaf(p.y, ctr[rr].y, fmaf(p.x, ctr[rr].x, -p.w)));
            const bool pr = e >= thr[rr];
            const uint64_t bal = __ballot(pr);
            if (pr) {
                const int within = __builtin_amdgcn_mbcnt_hi(
                    (uint32_t)(bal >> 32), __builtin_amdgcn_mbcnt_lo((uint32_t)bal, 0u));
                const int pos = base[rr] + within;
                if (pos < 64) surv[wave][rr][pos] = (uint32_t)m;
            }
            base[rr] += (int)__popcll(bal);
        }
    }
    asm volatile("s_waitcnt lgkmcnt(0)" ::: "memory");
    // ---- select exact top-32 per row (EXACT d-keys; FULLY UNROLLED — rule #20) ----
    uint32_t mrow[4];
    #pragma unroll
    for (int rr = 0; rr < 4; ++rr) {
        const int S = base[rr];                 // wave-uniform
        const float4 cc = ctr[rr];
        uint32_t myidx;
        if (S <= 64) {
            const float cw2 = cc.w + cc.w;      // exact |c|^2
            uint64_t key = 0ull;
            if (lane < S) {
                const int m = (int)surv[wave][rr][lane];
                const float4 p = xs[m];
                const float inner = fmaf(p.z, cc.z, fmaf(p.y, cc.y, p.x * cc.x));
                const float d = fmaf(2.0f, inner, -cw2) - (p.w + p.w);
                const uint32_t u  = __float_as_uint(d);
                const uint32_t kh = u ^ (uint32_t)(((int32_t)u >> 31) | 0x80000000);
                key = ((uint64_t)kh << 32) | (uint32_t)(~(uint32_t)m);
            }
            key = top32_split(key, lane);
            myidx = ~(uint32_t)key;
        } else {
            myidx = knn_row_serial(xs, nbase + rr, lane);
        }
        mrow[rr] = myidx;
        if (lane < KNB) idx_out[((size_t)b * NPTS + nbase + rr) * KNB + lane] = (int)myidx;
    }
    // ---- stats: neighbor moments, 2 rows per pass (lane halves) ----
    #pragma unroll
    for (int pr = 0; pr < 2; ++pr) {
        const int r0 = pr * 2, r1 = pr * 2 + 1;
        const uint32_t mhi = __shfl(mrow[r1], lane & 31);
        const uint32_t mm  = (lane < 32) ? mrow[r0] : mhi;
        const float4 p = xs[mm];
        const float cx = (lane < 32) ? ctr[r0].x : ctr[r1].x;
        const float cy = (lane < 32) ? ctr[r0].y : ctr[r1].y;
        const float cz = (lane < 32) ? ctr[r0].z : ctr[r1].z;
        Sp0 += p.x; Sp1 += p.y; Sp2 += p.z;
        Spp00 = fmaf(p.x, p.x, Spp00); Spp01 = fmaf(p.x, p.y, Spp01);
        Spp02 = fmaf(p.x, p.z, Spp02); Spp11 = fmaf(p.y, p.y, Spp11);
        Spp12 = fmaf(p.y, p.z, Spp12); Spp22 = fmaf(p.z, p.z, Spp22);
        Scp00 = fmaf(cx, p.x, Scp00); Scp01 = fmaf(cx, p.y, Scp01); Scp02 = fmaf(cx, p.z, Scp02);
        Scp10 = fmaf(cy, p.x, Scp10); Scp11 = fmaf(cy, p.y, Scp11); Scp12 = fmaf(cy, p.z, Scp12);
        Scp20 = fmaf(cz, p.x, Scp20); Scp21 = fmaf(cz, p.y, Scp21); Scp22 = fmaf(cz, p.z, Scp22);
    }
    // ---- center moments (uniform across lanes) ----
    #pragma unroll
    for (int rr = 0; rr < 4; ++rr) {
        const float4 cc = ctr[rr];
        Sc0 += cc.x; Sc1 += cc.y; Sc2 += cc.z;
        Scc00 = fmaf(cc.x, cc.x, Scc00); Scc01 = fmaf(cc.x, cc.y, Scc01);
        Scc02 = fmaf(cc.x, cc.z, Scc02); Scc11 = fmaf(cc.y, cc.y, Scc11);
        Scc12 = fmaf(cc.y, cc.z, Scc12); Scc22 = fmaf(cc.z, cc.z, Scc22);
    }
    // ---- butterfly-reduce neighbor moments over all 64 lanes ----
#define RED6(v) { v += __shfl_xor(v, 1); v += __shfl_xor(v, 2); v += __shfl_xor(v, 4); \
                  v += __shfl_xor(v, 8); v += __shfl_xor(v, 16); v += __shfl_xor(v, 32); }
    RED6(Sp0) RED6(Sp1) RED6(Sp2)
    RED6(Spp00) RED6(Spp01) RED6(Spp02) RED6(Spp11) RED6(Spp12) RED6(Spp22)
    RED6(Scp00) RED6(Scp01) RED6(Scp02) RED6(Scp10) RED6(Scp11) RED6(Scp12)
    RED6(Scp20) RED6(Scp21) RED6(Scp22)
#undef RED6
    // ---- finalize per channel (lane = channel) ----
    const float s = fmaf(w1b2, Sp2, fmaf(w1b1, Sp1, w1b0 * Sp0)) +
                    32.0f * fmaf(w1a2, Sc2, fmaf(w1a1, Sc1, w1a0 * Sc0));
    const float qA = w1a0 * w1a0 * Scc00 + w1a1 * w1a1 * Scc11 + w1a2 * w1a2 * Scc22 +
                     2.0f * (w1a0 * w1a1 * Scc01 + w1a0 * w1a2 * Scc02 + w1a1 * w1a2 * Scc12);
    const float qC = w1a0 * (w1b0 * Scp00 + w1b1 * Scp01 + w1b2 * Scp02) +
                     w1a1 * (w1b0 * Scp10 + w1b1 * Scp11 + w1b2 * Scp12) +
                     w1a2 * (w1b0 * Scp20 + w1b1 * Scp21 + w1b2 * Scp22);
    const float qB = w1b0 * w1b0 * Spp00 + w1b1 * w1b1 * Spp11 + w1b2 * w1b2 * Spp22 +
                     2.0f * (w1b0 * w1b1 * Spp01 + w1b0 * w1b2 * Spp02 + w1b1 * w1b2 * Spp12);
    const float q = fmaf(32.0f, qA, fmaf(2.0f, qC, qB));
    // ---- block reduce (alias red onto surv) + global atomics ----
    __syncthreads();
    float* red = (float*)&surv[0][0][0];            // [16][2][64] floats = 8 KB
    red[(wave * 2 + 0) * NCH + lane] = s;
    red[(wave * 2 + 1) * NCH + lane] = q;
    __syncthreads();
    if (threadIdx.x < NCH) {
        float S = 0.f, Q = 0.f;
        for (int w = 0; w < 16; ++w) {
            S += red[(w * 2 + 0) * NCH + threadIdx.x];
            Q += red[(w * 2 + 1) * NCH + threadIdx.x];
        }
        atomicAdd(&stats[threadIdx.x], S);
        atomicAdd(&stats[NCH + threadIdx.x], Q);
    }
}

// ---------------- K2: conv1+BN1+LReLU -> conv2 (MFMA); BN2 stats + per-(n,o) max/min ----------------
// R8's conv VERBATIM (best measured: ~43.5 us): f32 float4 xs, plain launch_bounds(256),
// idx prefetch, bbs-all-rows upfront, f32x4 LDS weight reads, serial in-loop gathers.
__global__ __launch_bounds__(256) void conv_kernel(const float* __restrict__ x,
                                                   const float* __restrict__ W1,
                                                   const float* __restrict__ W2,
                                                   const float* __restrict__ g1,
                                                   const float* __restrict__ be1,
                                                   const int* __restrict__ idx,
                                                   float* __restrict__ stats,
                                                   uint32_t* __restrict__ mm) {
    const int b  = blockIdx.x >> 7;
    const int n0 = (blockIdx.x & 127) * 32;
    __shared__ float4 xs[NPTS];                              // 64 KB
    __shared__ float bbs[4][8][NCH];                         // 8 KB per-wave base'
    __shared__ float wbx[NCH], wby[NCH], wbz[NCH];
    __shared__ float red[4 * 2 * NCH];
    const float* xb = x + (size_t)b * 3 * NPTS;
    for (int m = threadIdx.x; m < NPTS; m += 256) {
        float v0 = xb[m], v1 = xb[NPTS + m], v2 = xb[2 * NPTS + m];
        xs[m] = make_float4(v0, v1, v2, 0.f);
    }
    const int wave = threadIdx.x >> 6;
    const int lane = threadIdx.x & 63;
    const int ow = lane & 15, gi = lane >> 4;
    const float inv = 1.0f / MCNT;
    // prefetch idx for all 8 rows (break load-use chains)
    int my[8];
    #pragma unroll
    for (int r = 0; r < 8; ++r)
        my[r] = (lane < KNB) ? idx[((size_t)b * NPTS + n0 + wave * 8 + r) * KNB + lane] : 0;
    // own-channel BN1 fold
    const float m1 = stats[lane] * inv;
    const float v1 = fmaf(-m1, m1, stats[NCH + lane] * inv);
    const float a1 = g1[lane] * rsqrtf(v1 + EPS);
    const float bb1 = fmaf(-m1, a1, be1[lane]);
    const float w1b0 = W1[lane * 6 + 3], w1b1 = W1[lane * 6 + 4], w1b2 = W1[lane * 6 + 5];
    const float w1a0p = a1 * (W1[lane * 6 + 0] - w1b0);
    const float w1a1p = a1 * (W1[lane * 6 + 1] - w1b1);
    const float w1a2p = a1 * (W1[lane * 6 + 2] - w1b2);
    if (wave == 0) { wbx[lane] = a1 * w1b0; wby[lane] = a1 * w1b1; wbz[lane] = a1 * w1b2; }
    // W2 B-fragments
    bf16x8 wf[4][2];
    #pragma unroll
    for (int ot = 0; ot < 4; ++ot)
        #pragma unroll
        for (int jt = 0; jt < 2; ++jt) {
            const float* src = W2 + (ot * 16 + ow) * NCH + jt * 32 + gi * 8;
            bf16x8 v;
            #pragma unroll
            for (int jj = 0; jj < 8; ++jj) v[jj] = (__bf16)src[jj];
            wf[ot][jt] = v;
        }
    __syncthreads();
    // all 8 rows' base' upfront
    #pragma unroll
    for (int r = 0; r < 8; ++r) {
        const float4 cc = xs[n0 + wave * 8 + r];
        bbs[wave][r][lane] = fmaf(cc.z, w1a2p, fmaf(cc.y, w1a1p, fmaf(cc.x, w1a0p, bb1)));
    }
    // per-lane folded w1b' for its 16 A-channels
    f32x4 wx[2][2], wy[2][2], wz[2][2];
    #pragma unroll
    for (int jt = 0; jt < 2; ++jt)
        #pragma unroll
        for (int hh = 0; hh < 2; ++hh) {
            const int ch = jt * 32 + gi * 8 + hh * 4;
            wx[jt][hh] = *reinterpret_cast<const f32x4*>(&wbx[ch]);
            wy[jt][hh] = *reinterpret_cast<const f32x4*>(&wby[ch]);
            wz[jt][hh] = *reinterpret_cast<const f32x4*>(&wbz[ch]);
        }
    float sA[4] = {0.f, 0.f, 0.f, 0.f}, sQ[4] = {0.f, 0.f, 0.f, 0.f};
    for (int r = 0; r < 8; ++r) {
        const int n = n0 + wave * 8 + r;
        f32x4 ba[2][2];
        #pragma unroll
        for (int jt = 0; jt < 2; ++jt)
            #pragma unroll
            for (int hh = 0; hh < 2; ++hh)
                ba[jt][hh] = *reinterpret_cast<const f32x4*>(&bbs[wave][r][jt * 32 + gi * 8 + hh * 4]);
        f32x4 acc[2][4] = {};
        #pragma unroll
        for (int mt = 0; mt < 2; ++mt) {
            const int mb = (int)__shfl(my[r], mt * 16 + ow);
            const float4 pm = xs[mb];
            bf16x8 af[2];
            #pragma unroll
            for (int jt = 0; jt < 2; ++jt) {
                bf16x8 v;
                #pragma unroll
                for (int jj = 0; jj < 8; ++jj) {
                    float p = fmaf(pm.z, wz[jt][jj >> 2][jj & 3],
                              fmaf(pm.y, wy[jt][jj >> 2][jj & 3],
                              fmaf(pm.x, wx[jt][jj >> 2][jj & 3], ba[jt][jj >> 2][jj & 3])));
                    p = fmaxf(p, SLOPE * p);
                    v[jj] = (__bf16)p;
                }
                af[jt] = v;
            }
            #pragma unroll
            for (int jt = 0; jt < 2; ++jt)
                #pragma unroll
                for (int ot = 0; ot < 4; ++ot)
                    acc[mt][ot] = __builtin_amdgcn_mfma_f32_16x16x32_bf16(af[jt], wf[ot][jt],
                                                                          acc[mt][ot], 0, 0, 0);
        }
        // BN2 stats accumulation + per-(n,o) max/min over k
        #pragma unroll
        for (int ot = 0; ot < 4; ++ot) {
            float mx = -3.0e38f, mn = 3.0e38f;
            #pragma unroll
            for (int mt = 0; mt < 2; ++mt)
                #pragma unroll
                for (int rg = 0; rg < 4; ++rg) {
                    const float v = acc[mt][ot][rg];
                    sA[ot] += v; sQ[ot] = fmaf(v, v, sQ[ot]);
                    mx = fmaxf(mx, v); mn = fminf(mn, v);
                }
            mx = fmaxf(mx, __shfl_xor(mx, 16)); mx = fmaxf(mx, __shfl_xor(mx, 32));
            mn = fminf(mn, __shfl_xor(mn, 16)); mn = fminf(mn, __shfl_xor(mn, 32));
            if (lane < 16) {
                const uint32_t pk = (uint32_t)__builtin_bit_cast(uint16_t, (__bf16)mx) |
                                    ((uint32_t)__builtin_bit_cast(uint16_t, (__bf16)mn) << 16);
                mm[((size_t)b * NPTS + n) * 64 + ot * 16 + lane] = pk;
            }
        }
    }
    #pragma unroll
    for (int ot = 0; ot < 4; ++ot) {
        sA[ot] += __shfl_xor(sA[ot], 16); sA[ot] += __shfl_xor(sA[ot], 32);
        sQ[ot] += __shfl_xor(sQ[ot], 16); sQ[ot] += __shfl_xor(sQ[ot], 32);
    }
    if (lane < 16) {
        #pragma unroll
        for (int ot = 0; ot < 4; ++ot) {
            red[(wave * 2 + 0) * NCH + ot * 16 + lane] = sA[ot];
            red[(wave * 2 + 1) * NCH + ot * 16 + lane] = sQ[ot];
        }
    }
    __syncthreads();
    if (threadIdx.x < NCH) {
        float S = 0.f, Q = 0.f;
        for (int w = 0; w < 4; ++w) {
            S += red[(w * 2 + 0) * NCH + threadIdx.x];
            Q += red[(w * 2 + 1) * NCH + threadIdx.x];
        }
        atomicAdd(&stats[128 + threadIdx.x], S);
        atomicAdd(&stats[192 + threadIdx.x], Q);
    }
}

// ---------------- K3: finalize BN2 + LReLU (max folded via monotonicity) ----------------
__global__ __launch_bounds__(256) void final_kernel(const uint32_t* __restrict__ mm,
                                                    const float* __restrict__ stats,
                                                    const float* __restrict__ g2,
                                                    const float* __restrict__ be2,
                                                    float* __restrict__ out) {
    const int b  = blockIdx.x >> 7;
    const int n0 = (blockIdx.x & 127) * 32;
    __shared__ uint32_t ms[32 * 65];
    const uint32_t* src = mm + ((size_t)b * NPTS + n0) * 64;
    for (int i = threadIdx.x; i < 32 * 64; i += 256)
        ms[(i >> 6) * 65 + (i & 63)] = src[i];
    __syncthreads();
    const int o  = threadIdx.x >> 2;
    const int ns = (threadIdx.x & 3) * 8;
    const float inv = 1.0f / MCNT;
    const float m2 = stats[128 + o] * inv;
    const float v2 = fmaf(-m2, m2, stats[192 + o] * inv);
    const float a2 = g2[o] * rsqrtf(v2 + EPS);
    const float bb2 = fmaf(-m2, a2, be2[o]);
    float* dst = out + ((size_t)b * NCH + o) * NPTS + n0 + ns;
    #pragma unroll
    for (int j = 0; j < 8; ++j) {
        const uint32_t u = ms[(ns + j) * 65 + o];
        const float mx = __uint_as_float(u << 16);
        const float mn = __uint_as_float(u & 0xFFFF0000u);
        const float sel = (a2 >= 0.f) ? mx : mn;
        float h = fmaf(a2, sel, bb2);
        h = (h >= 0.f) ? h : SLOPE * h;
        dst[j] = h;
    }
}

extern "C" void kernel_launch(void* const* d_in, const int* in_sizes, int n_in,
                              void* d_out, int out_size, void* d_ws, size_t ws_size,
                              hipStream_t stream) {
    (void)in_sizes; (void)n_in; (void)out_size; (void)ws_size;
    const float* x   = (const float*)d_in[0];
    const float* W1  = (const float*)d_in[1];
    const float* g1  = (const float*)d_in[2];
    const float* be1 = (const float*)d_in[3];
    const float* W2  = (const float*)d_in[4];
    const float* g2  = (const float*)d_in[5];
    const float* be2 = (const float*)d_in[6];
    float* out   = (float*)d_out;
    float* stats = (float*)d_ws;                            // 4 KB page
    int*   idx   = (int*)((char*)d_ws + 4096);              // 4 MB
    uint32_t* mm = (uint32_t*)((char*)d_ws + 4096 + (size_t)NPTS * 8 * KNB * 4); // 8 MB
    hipMemsetAsync(d_ws, 0, 4096, stream);
    knn_kernel<<<dim3(512), dim3(1024), 0, stream>>>(x, W1, idx, stats);
    conv_kernel<<<dim3(1024), dim3(256), 0, stream>>>(x, W1, W2, g1, be1, idx, stats, mm);
    final_kernel<<<dim3(1024), dim3(256), 0, stream>>>(mm, stats, g2, be2, out);
}

// Round 16
// 140.640 us; speedup vs baseline: 1.1219x; 1.1219x over previous
//
#include <hip/hip_runtime.h>
#include <stdint.h>

#define NPTS 4096
#define KNB  32
#define NCH  64
#define EPS  1e-5f
#define SLOPE 0.2f
#define MCNT 1048576.0f   // B*N*K = 8*4096*32
#define GMARG 1e-3f       // conservative survivor-gate margin (>> 2*fp32 err of e)

typedef __attribute__((ext_vector_type(4))) float f32x4;
typedef __attribute__((ext_vector_type(8))) __bf16 bf16x8;

__device__ __forceinline__ float bflo(uint32_t u) { return __uint_as_float(u << 16); }
__device__ __forceinline__ float bfhi(uint32_t u) { return __uint_as_float(u & 0xffff0000u); }
__device__ __forceinline__ uint32_t bfbits(float v) {
    return (uint32_t)__builtin_bit_cast(uint16_t, (__bf16)v);
}

// ---------- in-register bitonic sort, 64 f32 (one per lane), descending ----------
__device__ __forceinline__ float sortf_desc(float v, int lane) {
    #pragma unroll
    for (int k = 2; k <= 64; k <<= 1) {
        #pragma unroll
        for (int j = k >> 1; j > 0; j >>= 1) {
            const float o = __shfl_xor(v, j);
            const bool up = ((lane & k) == 0) == ((lane & j) == 0);
            const float mx = fmaxf(v, o), mn = fminf(v, o);
            v = up ? mx : mn;
        }
    }
    return v;
}

// ---------- top-32 set of 64 u64 keys: 15-stage half-sorts + bitonic split ----------
__device__ __forceinline__ uint64_t top32_split(uint64_t v, int lane) {
    #pragma unroll
    for (int k = 2; k <= 32; k <<= 1) {
        #pragma unroll
        for (int j = k >> 1; j > 0; j >>= 1) {
            const uint64_t o = __shfl_xor((unsigned long long)v, j);
            const bool dirDesc = ((lane & k) == 0);
            const bool lower   = ((lane & j) == 0);
            const uint64_t mx = v > o ? v : o;
            const uint64_t mn = v > o ? o : v;
            v = (dirDesc == lower) ? mx : mn;
        }
    }
    const uint64_t o = __shfl_xor((unsigned long long)v, 32);
    return v > o ? v : o;
}

// ---------- serial-insertion fallback (exact R4 d-ordering; xs.w = 0.5*|p|^2) ----------
__device__ __noinline__ uint32_t knn_row_serial(const float4* xs, int n, int lane) {
    const float4 ctr = xs[n];
    const float cw2 = ctr.w + ctr.w;            // exact |c|^2
    uint32_t lh = 0u, ll = 0u;
    uint64_t tau = 0ull;
    for (int c = 0; c < 64; ++c) {
        const int m = (c << 6) + lane;
        const float4 p = xs[m];
        const float inner = fmaf(p.z, ctr.z, fmaf(p.y, ctr.y, p.x * ctr.x));
        const float d = fmaf(2.0f, inner, -cw2) - (p.w + p.w);
        const uint32_t u  = __float_as_uint(d);
        const uint32_t kh = u ^ (uint32_t)(((int32_t)u >> 31) | 0x80000000);
        const uint32_t kl = ~(uint32_t)m;
        const uint64_t key = ((uint64_t)kh << 32) | kl;
        uint64_t cand = __ballot(key > tau);
        while (cand) {
            const int src = __ffsll((unsigned long long)cand) - 1;
            cand &= cand - 1;
            const uint32_t ch  = __shfl(kh, src);
            const uint32_t cl2 = __shfl(kl, src);
            const uint64_t ck = ((uint64_t)ch << 32) | cl2;
            if (ck <= tau) continue;
            const uint64_t lk = ((uint64_t)lh << 32) | ll;
            const bool take = lk < ck;
            const uint64_t tb = __ballot(take);
            const int pos = __ffsll((unsigned long long)tb) - 1;
            const uint32_t sh = __shfl_up(lh, 1);
            const uint32_t sl = __shfl_up(ll, 1);
            if (take) { lh = sh; ll = sl; }
            if (lane == pos) { lh = ch; ll = cl2; }
            tau = ((uint64_t)__shfl(lh, 31) << 32) | __shfl(ll, 31);
        }
    }
    return ~ll;
}

// ---------------- K1: exact kNN (e-gate + exact-d select) + conv1 BN stats ----------------
// R10/R14 config VERBATIM (4x measured ~85 us): arg2=8 REQUESTS 8 waves/EU (occ 54%);
// the resulting VGPR-32 cap costs ~2MB spill, cheaper than the 33%-occ default (R15).
__global__ __launch_bounds__(1024, 8) void knn_kernel(const float* __restrict__ x,
                                                      const float* __restrict__ W1,
                                                      int* __restrict__ idx_out,
                                                      float* __restrict__ stats) {
    const int b  = blockIdx.x >> 6;
    const int n0 = (blockIdx.x & 63) * 64;
    __shared__ float4 xs[NPTS];                 // 64 KB; .w = 0.5*|p|^2
    __shared__ uint32_t surv[16][4][64];        // 16 KB (aliased as `red` at the end)
    const float* xb = x + (size_t)b * 3 * NPTS;
    for (int m = threadIdx.x; m < NPTS; m += 1024) {
        float v0 = xb[m], v1 = xb[NPTS + m], v2 = xb[2 * NPTS + m];
        xs[m] = make_float4(v0, v1, v2, 0.5f * fmaf(v2, v2, fmaf(v1, v1, v0 * v0)));
    }
    __syncthreads();
    const int wave = threadIdx.x >> 6;
    const int lane = threadIdx.x & 63;
    // per-lane conv1 weights (lane = channel)
    const float w1b0 = W1[lane * 6 + 3], w1b1 = W1[lane * 6 + 4], w1b2 = W1[lane * 6 + 5];
    const float w1a0 = W1[lane * 6 + 0] - w1b0;
    const float w1a1 = W1[lane * 6 + 1] - w1b1;
    const float w1a2 = W1[lane * 6 + 2] - w1b2;
    // moment accumulators
    float Sc0 = 0, Sc1 = 0, Sc2 = 0;
    float Scc00 = 0, Scc01 = 0, Scc02 = 0, Scc11 = 0, Scc12 = 0, Scc22 = 0;
    float Sp0 = 0, Sp1 = 0, Sp2 = 0;
    float Spp00 = 0, Spp01 = 0, Spp02 = 0, Spp11 = 0, Spp12 = 0, Spp22 = 0;
    float Scp00 = 0, Scp01 = 0, Scp02 = 0, Scp10 = 0, Scp11 = 0, Scp12 = 0,
          Scp20 = 0, Scp21 = 0, Scp22 = 0;

    const int nbase = n0 + wave * 4;
    float4 ctr[4];
    float lmax[4];
    #pragma unroll
    for (int rr = 0; rr < 4; ++rr) { ctr[rr] = xs[nbase + rr]; lmax[rr] = -3.0e38f; }
    // ---- pass A: per-lane max of e = p.c - 0.5|p|^2 (cheap gate metric) ----
    #pragma unroll 4
    for (int c = 0; c < 64; ++c) {
        const float4 p = xs[(c << 6) + lane];
        #pragma unroll
        for (int rr = 0; rr < 4; ++rr) {
            const float e = fmaf(p.z, ctr[rr].z, fmaf(p.y, ctr[rr].y, fmaf(p.x, ctr[rr].x, -p.w)));
            lmax[rr] = fmaxf(lmax[rr], e);
        }
    }
    // ---- threshold = 32nd largest lane-max, minus conservative margin ----
    float thr[4];
    #pragma unroll
    for (int rr = 0; rr < 4; ++rr)
        thr[rr] = __shfl(sortf_desc(lmax[rr], lane), 31) - GMARG;
    // ---- pass B: compact survivor indices (gate in e-metric, superset of top-32) ----
    int base[4] = {0, 0, 0, 0};
    #pragma unroll 2
    for (int c = 0; c < 64; ++c) {
        const int m = (c << 6) + lane;
        const float4 p = xs[m];
        #pragma unroll
        for (int rr = 0; rr < 4; ++rr) {
            const float e = fmaf(p.z, ctr[rr].z, fmaf(p.y, ctr[rr].y, fmaf(p.x, ctr[rr].x, -p.w)));
            const bool pr = e >= thr[rr];
            const uint64_t bal = __ballot(pr);
            if (pr) {
                const int within = __builtin_amdgcn_mbcnt_hi(
                    (uint32_t)(bal >> 32), __builtin_amdgcn_mbcnt_lo((uint32_t)bal, 0u));
                const int pos = base[rr] + within;
                if (pos < 64) surv[wave][rr][pos] = (uint32_t)m;
            }
            base[rr] += (int)__popcll(bal);
        }
    }
    asm volatile("s_waitcnt lgkmcnt(0)" ::: "memory");
    // ---- select exact top-32 per row (EXACT d-keys; FULLY UNROLLED — rule #20) ----
    uint32_t mrow[4];
    #pragma unroll
    for (int rr = 0; rr < 4; ++rr) {
        const int S = base[rr];                 // wave-uniform
        const float4 cc = ctr[rr];
        uint32_t myidx;
        if (S <= 64) {
            const float cw2 = cc.w + cc.w;      // exact |c|^2
            uint64_t key = 0ull;
            if (lane < S) {
                const int m = (int)surv[wave][rr][lane];
                const float4 p = xs[m];
                const float inner = fmaf(p.z, cc.z, fmaf(p.y, cc.y, p.x * cc.x));
                const float d = fmaf(2.0f, inner, -cw2) - (p.w + p.w);
                const uint32_t u  = __float_as_uint(d);
                const uint32_t kh = u ^ (uint32_t)(((int32_t)u >> 31) | 0x80000000);
                key = ((uint64_t)kh << 32) | (uint32_t)(~(uint32_t)m);
            }
            key = top32_split(key, lane);
            myidx = ~(uint32_t)key;
        } else {
            myidx = knn_row_serial(xs, nbase + rr, lane);
        }
        mrow[rr] = myidx;
        if (lane < KNB) idx_out[((size_t)b * NPTS + nbase + rr) * KNB + lane] = (int)myidx;
    }
    // ---- stats: neighbor moments, 2 rows per pass (lane halves) ----
    #pragma unroll
    for (int pr = 0; pr < 2; ++pr) {
        const int r0 = pr * 2, r1 = pr * 2 + 1;
        const uint32_t mhi = __shfl(mrow[r1], lane & 31);
        const uint32_t mm  = (lane < 32) ? mrow[r0] : mhi;
        const float4 p = xs[mm];
        const float cx = (lane < 32) ? ctr[r0].x : ctr[r1].x;
        const float cy = (lane < 32) ? ctr[r0].y : ctr[r1].y;
        const float cz = (lane < 32) ? ctr[r0].z : ctr[r1].z;
        Sp0 += p.x; Sp1 += p.y; Sp2 += p.z;
        Spp00 = fmaf(p.x, p.x, Spp00); Spp01 = fmaf(p.x, p.y, Spp01);
        Spp02 = fmaf(p.x, p.z, Spp02); Spp11 = fmaf(p.y, p.y, Spp11);
        Spp12 = fmaf(p.y, p.z, Spp12); Spp22 = fmaf(p.z, p.z, Spp22);
        Scp00 = fmaf(cx, p.x, Scp00); Scp01 = fmaf(cx, p.y, Scp01); Scp02 = fmaf(cx, p.z, Scp02);
        Scp10 = fmaf(cy, p.x, Scp10); Scp11 = fmaf(cy, p.y, Scp11); Scp12 = fmaf(cy, p.z, Scp12);
        Scp20 = fmaf(cz, p.x, Scp20); Scp21 = fmaf(cz, p.y, Scp21); Scp22 = fmaf(cz, p.z, Scp22);
    }
    // ---- center moments (uniform across lanes) ----
    #pragma unroll
    for (int rr = 0; rr < 4; ++rr) {
        const float4 cc = ctr[rr];
        Sc0 += cc.x; Sc1 += cc.y; Sc2 += cc.z;
        Scc00 = fmaf(cc.x, cc.x, Scc00); Scc01 = fmaf(cc.x, cc.y, Scc01);
        Scc02 = fmaf(cc.x, cc.z, Scc02); Scc11 = fmaf(cc.y, cc.y, Scc11);
        Scc12 = fmaf(cc.y, cc.z, Scc12); Scc22 = fmaf(cc.z, cc.z, Scc22);
    }
    // ---- butterfly-reduce neighbor moments over all 64 lanes ----
#define RED6(v) { v += __shfl_xor(v, 1); v += __shfl_xor(v, 2); v += __shfl_xor(v, 4); \
                  v += __shfl_xor(v, 8); v += __shfl_xor(v, 16); v += __shfl_xor(v, 32); }
    RED6(Sp0) RED6(Sp1) RED6(Sp2)
    RED6(Spp00) RED6(Spp01) RED6(Spp02) RED6(Spp11) RED6(Spp12) RED6(Spp22)
    RED6(Scp00) RED6(Scp01) RED6(Scp02) RED6(Scp10) RED6(Scp11) RED6(Scp12)
    RED6(Scp20) RED6(Scp21) RED6(Scp22)
#undef RED6
    // ---- finalize per channel (lane = channel) ----
    const float s = fmaf(w1b2, Sp2, fmaf(w1b1, Sp1, w1b0 * Sp0)) +
                    32.0f * fmaf(w1a2, Sc2, fmaf(w1a1, Sc1, w1a0 * Sc0));
    const float qA = w1a0 * w1a0 * Scc00 + w1a1 * w1a1 * Scc11 + w1a2 * w1a2 * Scc22 +
                     2.0f * (w1a0 * w1a1 * Scc01 + w1a0 * w1a2 * Scc02 + w1a1 * w1a2 * Scc12);
    const float qC = w1a0 * (w1b0 * Scp00 + w1b1 * Scp01 + w1b2 * Scp02) +
                     w1a1 * (w1b0 * Scp10 + w1b1 * Scp11 + w1b2 * Scp12) +
                     w1a2 * (w1b0 * Scp20 + w1b1 * Scp21 + w1b2 * Scp22);
    const float qB = w1b0 * w1b0 * Spp00 + w1b1 * w1b1 * Spp11 + w1b2 * w1b2 * Spp22 +
                     2.0f * (w1b0 * w1b1 * Spp01 + w1b0 * w1b2 * Spp02 + w1b1 * w1b2 * Spp12);
    const float q = fmaf(32.0f, qA, fmaf(2.0f, qC, qB));
    // ---- block reduce (alias red onto surv) + global atomics ----
    __syncthreads();
    float* red = (float*)&surv[0][0][0];            // [16][2][64] floats = 8 KB
    red[(wave * 2 + 0) * NCH + lane] = s;
    red[(wave * 2 + 1) * NCH + lane] = q;
    __syncthreads();
    if (threadIdx.x < NCH) {
        float S = 0.f, Q = 0.f;
        for (int w = 0; w < 16; ++w) {
            S += red[(w * 2 + 0) * NCH + threadIdx.x];
            Q += red[(w * 2 + 1) * NCH + threadIdx.x];
        }
        atomicAdd(&stats[threadIdx.x], S);
        atomicAdd(&stats[NCH + threadIdx.x], Q);
    }
}

// ---------------- K2: conv1+BN1+LReLU -> conv2 (MFMA); BN2 stats + per-(n,o) max/min ----------------
// R8 structure with ONE change: bf16-packed xs (32 KB) -> block LDS ~43 KB -> 3 blocks/CU
// (vs 2). Plain launch_bounds(256): register allocator unconstrained (R11/R12 lesson).
// Serial in-loop gathers (R13's prefetch-16 regressed). The only untested clean cell.
__global__ __launch_bounds__(256) void conv_kernel(const float* __restrict__ x,
                                                   const float* __restrict__ W1,
                                                   const float* __restrict__ W2,
                                                   const float* __restrict__ g1,
                                                   const float* __restrict__ be1,
                                                   const int* __restrict__ idx,
                                                   float* __restrict__ stats,
                                                   uint32_t* __restrict__ mm) {
    const int b  = blockIdx.x >> 7;
    const int n0 = (blockIdx.x & 127) * 32;
    __shared__ uint2 xs[NPTS];                               // 32 KB (bf16 x|y, z)
    __shared__ float bbs[4][8][NCH];                         // 8 KB per-wave base'
    __shared__ float wbx[NCH], wby[NCH], wbz[NCH];
    __shared__ float red[4 * 2 * NCH];
    const float* xb = x + (size_t)b * 3 * NPTS;
    for (int m = threadIdx.x; m < NPTS; m += 256) {
        const uint32_t bx = bfbits(xb[m]), by = bfbits(xb[NPTS + m]), bz = bfbits(xb[2 * NPTS + m]);
        xs[m] = make_uint2(bx | (by << 16), bz);
    }
    const int wave = threadIdx.x >> 6;
    const int lane = threadIdx.x & 63;
    const int ow = lane & 15, gi = lane >> 4;
    const float inv = 1.0f / MCNT;
    // prefetch idx for all 8 rows (break load-use chains)
    int my[8];
    #pragma unroll
    for (int r = 0; r < 8; ++r)
        my[r] = (lane < KNB) ? idx[((size_t)b * NPTS + n0 + wave * 8 + r) * KNB + lane] : 0;
    // own-channel BN1 fold
    const float m1 = stats[lane] * inv;
    const float v1 = fmaf(-m1, m1, stats[NCH + lane] * inv);
    const float a1 = g1[lane] * rsqrtf(v1 + EPS);
    const float bb1 = fmaf(-m1, a1, be1[lane]);
    const float w1b0 = W1[lane * 6 + 3], w1b1 = W1[lane * 6 + 4], w1b2 = W1[lane * 6 + 5];
    const float w1a0p = a1 * (W1[lane * 6 + 0] - w1b0);
    const float w1a1p = a1 * (W1[lane * 6 + 1] - w1b1);
    const float w1a2p = a1 * (W1[lane * 6 + 2] - w1b2);
    if (wave == 0) { wbx[lane] = a1 * w1b0; wby[lane] = a1 * w1b1; wbz[lane] = a1 * w1b2; }
    // W2 B-fragments
    bf16x8 wf[4][2];
    #pragma unroll
    for (int ot = 0; ot < 4; ++ot)
        #pragma unroll
        for (int jt = 0; jt < 2; ++jt) {
            const float* src = W2 + (ot * 16 + ow) * NCH + jt * 32 + gi * 8;
            bf16x8 v;
            #pragma unroll
            for (int jj = 0; jj < 8; ++jj) v[jj] = (__bf16)src[jj];
            wf[ot][jt] = v;
        }
    __syncthreads();
    // all 8 rows' base' upfront
    #pragma unroll
    for (int r = 0; r < 8; ++r) {
        const uint2 q = xs[n0 + wave * 8 + r];
        const float ccx = bflo(q.x), ccy = bfhi(q.x), ccz = bflo(q.y);
        bbs[wave][r][lane] = fmaf(ccz, w1a2p, fmaf(ccy, w1a1p, fmaf(ccx, w1a0p, bb1)));
    }
    // per-lane folded w1b' for its 16 A-channels
    f32x4 wx[2][2], wy[2][2], wz[2][2];
    #pragma unroll
    for (int jt = 0; jt < 2; ++jt)
        #pragma unroll
        for (int hh = 0; hh < 2; ++hh) {
            const int ch = jt * 32 + gi * 8 + hh * 4;
            wx[jt][hh] = *reinterpret_cast<const f32x4*>(&wbx[ch]);
            wy[jt][hh] = *reinterpret_cast<const f32x4*>(&wby[ch]);
            wz[jt][hh] = *reinterpret_cast<const f32x4*>(&wbz[ch]);
        }
    float sA[4] = {0.f, 0.f, 0.f, 0.f}, sQ[4] = {0.f, 0.f, 0.f, 0.f};
    for (int r = 0; r < 8; ++r) {
        const int n = n0 + wave * 8 + r;
        f32x4 ba[2][2];
        #pragma unroll
        for (int jt = 0; jt < 2; ++jt)
            #pragma unroll
            for (int hh = 0; hh < 2; ++hh)
                ba[jt][hh] = *reinterpret_cast<const f32x4*>(&bbs[wave][r][jt * 32 + gi * 8 + hh * 4]);
        f32x4 acc[2][4] = {};
        #pragma unroll
        for (int mt = 0; mt < 2; ++mt) {
            const int mb = (int)__shfl(my[r], mt * 16 + ow);
            const uint2 pm = xs[mb];
            const float pmx = bflo(pm.x), pmy = bfhi(pm.x), pmz = bflo(pm.y);
            bf16x8 af[2];
            #pragma unroll
            for (int jt = 0; jt < 2; ++jt) {
                bf16x8 v;
                #pragma unroll
                for (int jj = 0; jj < 8; ++jj) {
                    float p = fmaf(pmz, wz[jt][jj >> 2][jj & 3],
                              fmaf(pmy, wy[jt][jj >> 2][jj & 3],
                              fmaf(pmx, wx[jt][jj >> 2][jj & 3], ba[jt][jj >> 2][jj & 3])));
                    p = fmaxf(p, SLOPE * p);
                    v[jj] = (__bf16)p;
                }
                af[jt] = v;
            }
            #pragma unroll
            for (int jt = 0; jt < 2; ++jt)
                #pragma unroll
                for (int ot = 0; ot < 4; ++ot)
                    acc[mt][ot] = __builtin_amdgcn_mfma_f32_16x16x32_bf16(af[jt], wf[ot][jt],
                                                                          acc[mt][ot], 0, 0, 0);
        }
        // BN2 stats accumulation + per-(n,o) max/min over k
        #pragma unroll
        for (int ot = 0; ot < 4; ++ot) {
            float mx = -3.0e38f, mn = 3.0e38f;
            #pragma unroll
            for (int mt = 0; mt < 2; ++mt)
                #pragma unroll
                for (int rg = 0; rg < 4; ++rg) {
                    const float v = acc[mt][ot][rg];
                    sA[ot] += v; sQ[ot] = fmaf(v, v, sQ[ot]);
                    mx = fmaxf(mx, v); mn = fminf(mn, v);
                }
            mx = fmaxf(mx, __shfl_xor(mx, 16)); mx = fmaxf(mx, __shfl_xor(mx, 32));
            mn = fminf(mn, __shfl_xor(mn, 16)); mn = fminf(mn, __shfl_xor(mn, 32));
            if (lane < 16) {
                const uint32_t pk = (uint32_t)__builtin_bit_cast(uint16_t, (__bf16)mx) |
                                    ((uint32_t)__builtin_bit_cast(uint16_t, (__bf16)mn) << 16);
                mm[((size_t)b * NPTS + n) * 64 + ot * 16 + lane] = pk;
            }
        }
    }
    #pragma unroll
    for (int ot = 0; ot < 4; ++ot) {
        sA[ot] += __shfl_xor(sA[ot], 16); sA[ot] += __shfl_xor(sA[ot], 32);
        sQ[ot] += __shfl_xor(sQ[ot], 16); sQ[ot] += __shfl_xor(sQ[ot], 32);
    }
    if (lane < 16) {
        #pragma unroll
        for (int ot = 0; ot < 4; ++ot) {
            red[(wave * 2 + 0) * NCH + ot * 16 + lane] = sA[ot];
            red[(wave * 2 + 1) * NCH + ot * 16 + lane] = sQ[ot];
        }
    }
    __syncthreads();
    if (threadIdx.x < NCH) {
        float S = 0.f, Q = 0.f;
        for (int w = 0; w < 4; ++w) {
            S += red[(w * 2 + 0) * NCH + threadIdx.x];
            Q += red[(w * 2 + 1) * NCH + threadIdx.x];
        }
        atomicAdd(&stats[128 + threadIdx.x], S);
        atomicAdd(&stats[192 + threadIdx.x], Q);
    }
}

// ---------------- K3: finalize BN2 + LReLU (max folded via monotonicity) ----------------
__global__ __launch_bounds__(256) void final_kernel(const uint32_t* __restrict__ mm,
                                                    const float* __restrict__ stats,
                                                    const float* __restrict__ g2,
                                                    const float* __restrict__ be2,
                                                    float* __restrict__ out) {
    const int b  = blockIdx.x >> 7;
    const int n0 = (blockIdx.x & 127) * 32;
    __shared__ uint32_t ms[32 * 65];
    const uint32_t* src = mm + ((size_t)b * NPTS + n0) * 64;
    for (int i = threadIdx.x; i < 32 * 64; i += 256)
        ms[(i >> 6) * 65 + (i & 63)] = src[i];
    __syncthreads();
    const int o  = threadIdx.x >> 2;
    const int ns = (threadIdx.x & 3) * 8;
    const float inv = 1.0f / MCNT;
    const float m2 = stats[128 + o] * inv;
    const float v2 = fmaf(-m2, m2, stats[192 + o] * inv);
    const float a2 = g2[o] * rsqrtf(v2 + EPS);
    const float bb2 = fmaf(-m2, a2, be2[o]);
    float* dst = out + ((size_t)b * NCH + o) * NPTS + n0 + ns;
    #pragma unroll
    for (int j = 0; j < 8; ++j) {
        const uint32_t u = ms[(ns + j) * 65 + o];
        const float mx = __uint_as_float(u << 16);
        const float mn = __uint_as_float(u & 0xFFFF0000u);
        const float sel = (a2 >= 0.f) ? mx : mn;
        float h = fmaf(a2, sel, bb2);
        h = (h >= 0.f) ? h : SLOPE * h;
        dst[j] = h;
    }
}

extern "C" void kernel_launch(void* const* d_in, const int* in_sizes, int n_in,
                              void* d_out, int out_size, void* d_ws, size_t ws_size,
                              hipStream_t stream) {
    (void)in_sizes; (void)n_in; (void)out_size; (void)ws_size;
    const float* x   = (const float*)d_in[0];
    const float* W1  = (const float*)d_in[1];
    const float* g1  = (const float*)d_in[2];
    const float* be1 = (const float*)d_in[3];
    const float* W2  = (const float*)d_in[4];
    const float* g2  = (const float*)d_in[5];
    const float* be2 = (const float*)d_in[6];
    float* out   = (float*)d_out;
    float* stats = (float*)d_ws;                            // 4 KB page
    int*   idx   = (int*)((char*)d_ws + 4096);              // 4 MB
    uint32_t* mm = (uint32_t*)((char*)d_ws + 4096 + (size_t)NPTS * 8 * KNB * 4); // 8 MB
    hipMemsetAsync(d_ws, 0, 4096, stream);
    knn_kernel<<<dim3(512), dim3(1024), 0, stream>>>(x, W1, idx, stats);
    conv_kernel<<<dim3(1024), dim3(256), 0, stream>>>(x, W1, W2, g1, be1, idx, stats, mm);
    final_kernel<<<dim3(1024), dim3(256), 0, stream>>>(mm, stats, g2, be2, out);
}

// Round 17
// 133.172 us; speedup vs baseline: 1.1848x; 1.0561x over previous
//
#include <hip/hip_runtime.h>
#include <stdint.h>

#define NPTS 4096
#define KNB  32
#define NCH  64
#define EPS  1e-5f
#define SLOPE 0.2f
#define MCNT 1048576.0f   // B*N*K = 8*4096*32
#define GMARG 1e-3f       // conservative survivor-gate margin (>> 2*fp32 err of e)

typedef __attribute__((ext_vector_type(4))) float f32x4;
typedef __attribute__((ext_vector_type(8))) __bf16 bf16x8;

// ---------- in-register bitonic sort, 64 f32 (one per lane), descending ----------
__device__ __forceinline__ float sortf_desc(float v, int lane) {
    #pragma unroll
    for (int k = 2; k <= 64; k <<= 1) {
        #pragma unroll
        for (int j = k >> 1; j > 0; j >>= 1) {
            const float o = __shfl_xor(v, j);
            const bool up = ((lane & k) == 0) == ((lane & j) == 0);
            const float mx = fmaxf(v, o), mn = fminf(v, o);
            v = up ? mx : mn;
        }
    }
    return v;
}

// ---------- top-32 set of 64 u64 keys: 15-stage half-sorts + bitonic split ----------
__device__ __forceinline__ uint64_t top32_split(uint64_t v, int lane) {
    #pragma unroll
    for (int k = 2; k <= 32; k <<= 1) {
        #pragma unroll
        for (int j = k >> 1; j > 0; j >>= 1) {
            const uint64_t o = __shfl_xor((unsigned long long)v, j);
            const bool dirDesc = ((lane & k) == 0);
            const bool lower   = ((lane & j) == 0);
            const uint64_t mx = v > o ? v : o;
            const uint64_t mn = v > o ? o : v;
            v = (dirDesc == lower) ? mx : mn;
        }
    }
    const uint64_t o = __shfl_xor((unsigned long long)v, 32);
    return v > o ? v : o;
}

// ---------- serial-insertion fallback (exact R4 d-ordering; xs.w = 0.5*|p|^2) ----------
__device__ __noinline__ uint32_t knn_row_serial(const float4* xs, int n, int lane) {
    const float4 ctr = xs[n];
    const float cw2 = ctr.w + ctr.w;            // exact |c|^2
    uint32_t lh = 0u, ll = 0u;
    uint64_t tau = 0ull;
    for (int c = 0; c < 64; ++c) {
        const int m = (c << 6) + lane;
        const float4 p = xs[m];
        const float inner = fmaf(p.z, ctr.z, fmaf(p.y, ctr.y, p.x * ctr.x));
        const float d = fmaf(2.0f, inner, -cw2) - (p.w + p.w);
        const uint32_t u  = __float_as_uint(d);
        const uint32_t kh = u ^ (uint32_t)(((int32_t)u >> 31) | 0x80000000);
        const uint32_t kl = ~(uint32_t)m;
        const uint64_t key = ((uint64_t)kh << 32) | kl;
        uint64_t cand = __ballot(key > tau);
        while (cand) {
            const int src = __ffsll((unsigned long long)cand) - 1;
            cand &= cand - 1;
            const uint32_t ch  = __shfl(kh, src);
            const uint32_t cl2 = __shfl(kl, src);
            const uint64_t ck = ((uint64_t)ch << 32) | cl2;
            if (ck <= tau) continue;
            const uint64_t lk = ((uint64_t)lh << 32) | ll;
            const bool take = lk < ck;
            const uint64_t tb = __ballot(take);
            const int pos = __ffsll((unsigned long long)tb) - 1;
            const uint32_t sh = __shfl_up(lh, 1);
            const uint32_t sl = __shfl_up(ll, 1);
            if (take) { lh = sh; ll = sl; }
            if (lane == pos) { lh = ch; ll = cl2; }
            tau = ((uint64_t)__shfl(lh, 31) << 32) | __shfl(ll, 31);
        }
    }
    return ~ll;
}

// ---------------- K1: exact kNN (e-gate + exact-d select) + conv1 BN stats ----------------
// R14 config, ONE change: ctr stored as 3 scalars/row (12 VGPR vs 16); cw2 recomputed
// bit-identically in select (2*(0.5*ss)==ss exact). Demand 36 -> 32 = cap -> no spill,
// keeping arg2=8's 8 waves/EU (occ 54%).
__global__ __launch_bounds__(1024, 8) void knn_kernel(const float* __restrict__ x,
                                                      const float* __restrict__ W1,
                                                      int* __restrict__ idx_out,
                                                      float* __restrict__ stats) {
    const int b  = blockIdx.x >> 6;
    const int n0 = (blockIdx.x & 63) * 64;
    __shared__ float4 xs[NPTS];                 // 64 KB; .w = 0.5*|p|^2
    __shared__ uint32_t surv[16][4][64];        // 16 KB (aliased as `red` at the end)
    const float* xb = x + (size_t)b * 3 * NPTS;
    for (int m = threadIdx.x; m < NPTS; m += 1024) {
        float v0 = xb[m], v1 = xb[NPTS + m], v2 = xb[2 * NPTS + m];
        xs[m] = make_float4(v0, v1, v2, 0.5f * fmaf(v2, v2, fmaf(v1, v1, v0 * v0)));
    }
    __syncthreads();
    const int wave = threadIdx.x >> 6;
    const int lane = threadIdx.x & 63;
    // per-lane conv1 weights (lane = channel)
    const float w1b0 = W1[lane * 6 + 3], w1b1 = W1[lane * 6 + 4], w1b2 = W1[lane * 6 + 5];
    const float w1a0 = W1[lane * 6 + 0] - w1b0;
    const float w1a1 = W1[lane * 6 + 1] - w1b1;
    const float w1a2 = W1[lane * 6 + 2] - w1b2;
    // moment accumulators
    float Sc0 = 0, Sc1 = 0, Sc2 = 0;
    float Scc00 = 0, Scc01 = 0, Scc02 = 0, Scc11 = 0, Scc12 = 0, Scc22 = 0;
    float Sp0 = 0, Sp1 = 0, Sp2 = 0;
    float Spp00 = 0, Spp01 = 0, Spp02 = 0, Spp11 = 0, Spp12 = 0, Spp22 = 0;
    float Scp00 = 0, Scp01 = 0, Scp02 = 0, Scp10 = 0, Scp11 = 0, Scp12 = 0,
          Scp20 = 0, Scp21 = 0, Scp22 = 0;

    const int nbase = n0 + wave * 4;
    float ctx[4], cty[4], ctz[4];
    float lmax[4];
    #pragma unroll
    for (int rr = 0; rr < 4; ++rr) {
        const float4 cc = xs[nbase + rr];
        ctx[rr] = cc.x; cty[rr] = cc.y; ctz[rr] = cc.z;
        lmax[rr] = -3.0e38f;
    }
    // ---- pass A: per-lane max of e = p.c - 0.5|p|^2 (cheap gate metric) ----
    #pragma unroll 4
    for (int c = 0; c < 64; ++c) {
        const float4 p = xs[(c << 6) + lane];
        #pragma unroll
        for (int rr = 0; rr < 4; ++rr) {
            const float e = fmaf(p.z, ctz[rr], fmaf(p.y, cty[rr], fmaf(p.x, ctx[rr], -p.w)));
            lmax[rr] = fmaxf(lmax[rr], e);
        }
    }
    // ---- threshold = 32nd largest lane-max, minus conservative margin ----
    float thr[4];
    #pragma unroll
    for (int rr = 0; rr < 4; ++rr)
        thr[rr] = __shfl(sortf_desc(lmax[rr], lane), 31) - GMARG;
    // ---- pass B: compact survivor indices (gate in e-metric, superset of top-32) ----
    int base[4] = {0, 0, 0, 0};
    #pragma unroll 2
    for (int c = 0; c < 64; ++c) {
        const int m = (c << 6) + lane;
        const float4 p = xs[m];
        #pragma unroll
        for (int rr = 0; rr < 4; ++rr) {
            const float e = fmaf(p.z, ctz[rr], fmaf(p.y, cty[rr], fmaf(p.x, ctx[rr], -p.w)));
            const bool pr = e >= thr[rr];
            const uint64_t bal = __ballot(pr);
            if (pr) {
                const int within = __builtin_amdgcn_mbcnt_hi(
                    (uint32_t)(bal >> 32), __builtin_amdgcn_mbcnt_lo((uint32_t)bal, 0u));
                const int pos = base[rr] + within;
                if (pos < 64) surv[wave][rr][pos] = (uint32_t)m;
            }
            base[rr] += (int)__popcll(bal);
        }
    }
    asm volatile("s_waitcnt lgkmcnt(0)" ::: "memory");
    // ---- select exact top-32 per row (EXACT d-keys; FULLY UNROLLED — rule #20) ----
    uint32_t mrow[4];
    #pragma unroll
    for (int rr = 0; rr < 4; ++rr) {
        const int S = base[rr];                 // wave-uniform
        uint32_t myidx;
        if (S <= 64) {
            // cw2 == ctr.w+ctr.w bit-exactly: same fmaf chain as staging, 2*(0.5*v)==v
            const float cw2 = fmaf(ctz[rr], ctz[rr], fmaf(cty[rr], cty[rr], ctx[rr] * ctx[rr]));
            uint64_t key = 0ull;
            if (lane < S) {
                const int m = (int)surv[wave][rr][lane];
                const float4 p = xs[m];
                const float inner = fmaf(p.z, ctz[rr], fmaf(p.y, cty[rr], p.x * ctx[rr]));
                const float d = fmaf(2.0f, inner, -cw2) - (p.w + p.w);
                const uint32_t u  = __float_as_uint(d);
                const uint32_t kh = u ^ (uint32_t)(((int32_t)u >> 31) | 0x80000000);
                key = ((uint64_t)kh << 32) | (uint32_t)(~(uint32_t)m);
            }
            key = top32_split(key, lane);
            myidx = ~(uint32_t)key;
        } else {
            myidx = knn_row_serial(xs, nbase + rr, lane);
        }
        mrow[rr] = myidx;
        if (lane < KNB) idx_out[((size_t)b * NPTS + nbase + rr) * KNB + lane] = (int)myidx;
    }
    // ---- stats: neighbor moments, 2 rows per pass (lane halves) ----
    #pragma unroll
    for (int pr = 0; pr < 2; ++pr) {
        const int r0 = pr * 2, r1 = pr * 2 + 1;
        const uint32_t mhi = __shfl(mrow[r1], lane & 31);
        const uint32_t mm  = (lane < 32) ? mrow[r0] : mhi;
        const float4 p = xs[mm];
        const float cx = (lane < 32) ? ctx[r0] : ctx[r1];
        const float cy = (lane < 32) ? cty[r0] : cty[r1];
        const float cz = (lane < 32) ? ctz[r0] : ctz[r1];
        Sp0 += p.x; Sp1 += p.y; Sp2 += p.z;
        Spp00 = fmaf(p.x, p.x, Spp00); Spp01 = fmaf(p.x, p.y, Spp01);
        Spp02 = fmaf(p.x, p.z, Spp02); Spp11 = fmaf(p.y, p.y, Spp11);
        Spp12 = fmaf(p.y, p.z, Spp12); Spp22 = fmaf(p.z, p.z, Spp22);
        Scp00 = fmaf(cx, p.x, Scp00); Scp01 = fmaf(cx, p.y, Scp01); Scp02 = fmaf(cx, p.z, Scp02);
        Scp10 = fmaf(cy, p.x, Scp10); Scp11 = fmaf(cy, p.y, Scp11); Scp12 = fmaf(cy, p.z, Scp12);
        Scp20 = fmaf(cz, p.x, Scp20); Scp21 = fmaf(cz, p.y, Scp21); Scp22 = fmaf(cz, p.z, Scp22);
    }
    // ---- center moments (uniform across lanes) ----
    #pragma unroll
    for (int rr = 0; rr < 4; ++rr) {
        const float cx = ctx[rr], cy = cty[rr], cz = ctz[rr];
        Sc0 += cx; Sc1 += cy; Sc2 += cz;
        Scc00 = fmaf(cx, cx, Scc00); Scc01 = fmaf(cx, cy, Scc01);
        Scc02 = fmaf(cx, cz, Scc02); Scc11 = fmaf(cy, cy, Scc11);
        Scc12 = fmaf(cy, cz, Scc12); Scc22 = fmaf(cz, cz, Scc22);
    }
    // ---- butterfly-reduce neighbor moments over all 64 lanes ----
#define RED6(v) { v += __shfl_xor(v, 1); v += __shfl_xor(v, 2); v += __shfl_xor(v, 4); \
                  v += __shfl_xor(v, 8); v += __shfl_xor(v, 16); v += __shfl_xor(v, 32); }
    RED6(Sp0) RED6(Sp1) RED6(Sp2)
    RED6(Spp00) RED6(Spp01) RED6(Spp02) RED6(Spp11) RED6(Spp12) RED6(Spp22)
    RED6(Scp00) RED6(Scp01) RED6(Scp02) RED6(Scp10) RED6(Scp11) RED6(Scp12)
    RED6(Scp20) RED6(Scp21) RED6(Scp22)
#undef RED6
    // ---- finalize per channel (lane = channel) ----
    const float s = fmaf(w1b2, Sp2, fmaf(w1b1, Sp1, w1b0 * Sp0)) +
                    32.0f * fmaf(w1a2, Sc2, fmaf(w1a1, Sc1, w1a0 * Sc0));
    const float qA = w1a0 * w1a0 * Scc00 + w1a1 * w1a1 * Scc11 + w1a2 * w1a2 * Scc22 +
                     2.0f * (w1a0 * w1a1 * Scc01 + w1a0 * w1a2 * Scc02 + w1a1 * w1a2 * Scc12);
    const float qC = w1a0 * (w1b0 * Scp00 + w1b1 * Scp01 + w1b2 * Scp02) +
                     w1a1 * (w1b0 * Scp10 + w1b1 * Scp11 + w1b2 * Scp12) +
                     w1a2 * (w1b0 * Scp20 + w1b1 * Scp21 + w1b2 * Scp22);
    const float qB = w1b0 * w1b0 * Spp00 + w1b1 * w1b1 * Spp11 + w1b2 * w1b2 * Spp22 +
                     2.0f * (w1b0 * w1b1 * Spp01 + w1b0 * w1b2 * Spp02 + w1b1 * w1b2 * Spp12);
    const float q = fmaf(32.0f, qA, fmaf(2.0f, qC, qB));
    // ---- block reduce (alias red onto surv) + global atomics ----
    __syncthreads();
    float* red = (float*)&surv[0][0][0];            // [16][2][64] floats = 8 KB
    red[(wave * 2 + 0) * NCH + lane] = s;
    red[(wave * 2 + 1) * NCH + lane] = q;
    __syncthreads();
    if (threadIdx.x < NCH) {
        float S = 0.f, Q = 0.f;
        for (int w = 0; w < 16; ++w) {
            S += red[(w * 2 + 0) * NCH + threadIdx.x];
            Q += red[(w * 2 + 1) * NCH + threadIdx.x];
        }
        atomicAdd(&stats[threadIdx.x], S);
        atomicAdd(&stats[NCH + threadIdx.x], Q);
    }
}

// ---------------- K2: conv1+BN1+LReLU -> conv2 (MFMA); BN2 stats + per-(n,o) max/min ----------------
// R8/R14 conv VERBATIM (best measured ~43.5 us across all variants tried).
__global__ __launch_bounds__(256) void conv_kernel(const float* __restrict__ x,
                                                   const float* __restrict__ W1,
                                                   const float* __restrict__ W2,
                                                   const float* __restrict__ g1,
                                                   const float* __restrict__ be1,
                                                   const int* __restrict__ idx,
                                                   float* __restrict__ stats,
                                                   uint32_t* __restrict__ mm) {
    const int b  = blockIdx.x >> 7;
    const int n0 = (blockIdx.x & 127) * 32;
    __shared__ float4 xs[NPTS];                              // 64 KB
    __shared__ float bbs[4][8][NCH];                         // 8 KB per-wave base'
    __shared__ float wbx[NCH], wby[NCH], wbz[NCH];
    __shared__ float red[4 * 2 * NCH];
    const float* xb = x + (size_t)b * 3 * NPTS;
    for (int m = threadIdx.x; m < NPTS; m += 256) {
        float v0 = xb[m], v1 = xb[NPTS + m], v2 = xb[2 * NPTS + m];
        xs[m] = make_float4(v0, v1, v2, 0.f);
    }
    const int wave = threadIdx.x >> 6;
    const int lane = threadIdx.x & 63;
    const int ow = lane & 15, gi = lane >> 4;
    const float inv = 1.0f / MCNT;
    // prefetch idx for all 8 rows (break load-use chains)
    int my[8];
    #pragma unroll
    for (int r = 0; r < 8; ++r)
        my[r] = (lane < KNB) ? idx[((size_t)b * NPTS + n0 + wave * 8 + r) * KNB + lane] : 0;
    // own-channel BN1 fold
    const float m1 = stats[lane] * inv;
    const float v1 = fmaf(-m1, m1, stats[NCH + lane] * inv);
    const float a1 = g1[lane] * rsqrtf(v1 + EPS);
    const float bb1 = fmaf(-m1, a1, be1[lane]);
    const float w1b0 = W1[lane * 6 + 3], w1b1 = W1[lane * 6 + 4], w1b2 = W1[lane * 6 + 5];
    const float w1a0p = a1 * (W1[lane * 6 + 0] - w1b0);
    const float w1a1p = a1 * (W1[lane * 6 + 1] - w1b1);
    const float w1a2p = a1 * (W1[lane * 6 + 2] - w1b2);
    if (wave == 0) { wbx[lane] = a1 * w1b0; wby[lane] = a1 * w1b1; wbz[lane] = a1 * w1b2; }
    // W2 B-fragments
    bf16x8 wf[4][2];
    #pragma unroll
    for (int ot = 0; ot < 4; ++ot)
        #pragma unroll
        for (int jt = 0; jt < 2; ++jt) {
            const float* src = W2 + (ot * 16 + ow) * NCH + jt * 32 + gi * 8;
            bf16x8 v;
            #pragma unroll
            for (int jj = 0; jj < 8; ++jj) v[jj] = (__bf16)src[jj];
            wf[ot][jt] = v;
        }
    __syncthreads();
    // all 8 rows' base' upfront
    #pragma unroll
    for (int r = 0; r < 8; ++r) {
        const float4 cc = xs[n0 + wave * 8 + r];
        bbs[wave][r][lane] = fmaf(cc.z, w1a2p, fmaf(cc.y, w1a1p, fmaf(cc.x, w1a0p, bb1)));
    }
    // per-lane folded w1b' for its 16 A-channels
    f32x4 wx[2][2], wy[2][2], wz[2][2];
    #pragma unroll
    for (int jt = 0; jt < 2; ++jt)
        #pragma unroll
        for (int hh = 0; hh < 2; ++hh) {
            const int ch = jt * 32 + gi * 8 + hh * 4;
            wx[jt][hh] = *reinterpret_cast<const f32x4*>(&wbx[ch]);
            wy[jt][hh] = *reinterpret_cast<const f32x4*>(&wby[ch]);
            wz[jt][hh] = *reinterpret_cast<const f32x4*>(&wbz[ch]);
        }
    float sA[4] = {0.f, 0.f, 0.f, 0.f}, sQ[4] = {0.f, 0.f, 0.f, 0.f};
    for (int r = 0; r < 8; ++r) {
        const int n = n0 + wave * 8 + r;
        f32x4 ba[2][2];
        #pragma unroll
        for (int jt = 0; jt < 2; ++jt)
            #pragma unroll
            for (int hh = 0; hh < 2; ++hh)
                ba[jt][hh] = *reinterpret_cast<const f32x4*>(&bbs[wave][r][jt * 32 + gi * 8 + hh * 4]);
        f32x4 acc[2][4] = {};
        #pragma unroll
        for (int mt = 0; mt < 2; ++mt) {
            const int mb = (int)__shfl(my[r], mt * 16 + ow);
            const float4 pm = xs[mb];
            bf16x8 af[2];
            #pragma unroll
            for (int jt = 0; jt < 2; ++jt) {
                bf16x8 v;
                #pragma unroll
                for (int jj = 0; jj < 8; ++jj) {
                    float p = fmaf(pm.z, wz[jt][jj >> 2][jj & 3],
                              fmaf(pm.y, wy[jt][jj >> 2][jj & 3],
                              fmaf(pm.x, wx[jt][jj >> 2][jj & 3], ba[jt][jj >> 2][jj & 3])));
                    p = fmaxf(p, SLOPE * p);
                    v[jj] = (__bf16)p;
                }
                af[jt] = v;
            }
            #pragma unroll
            for (int jt = 0; jt < 2; ++jt)
                #pragma unroll
                for (int ot = 0; ot < 4; ++ot)
                    acc[mt][ot] = __builtin_amdgcn_mfma_f32_16x16x32_bf16(af[jt], wf[ot][jt],
                                                                          acc[mt][ot], 0, 0, 0);
        }
        // BN2 stats accumulation + per-(n,o) max/min over k
        #pragma unroll
        for (int ot = 0; ot < 4; ++ot) {
            float mx = -3.0e38f, mn = 3.0e38f;
            #pragma unroll
            for (int mt = 0; mt < 2; ++mt)
                #pragma unroll
                for (int rg = 0; rg < 4; ++rg) {
                    const float v = acc[mt][ot][rg];
                    sA[ot] += v; sQ[ot] = fmaf(v, v, sQ[ot]);
                    mx = fmaxf(mx, v); mn = fminf(mn, v);
                }
            mx = fmaxf(mx, __shfl_xor(mx, 16)); mx = fmaxf(mx, __shfl_xor(mx, 32));
            mn = fminf(mn, __shfl_xor(mn, 16)); mn = fminf(mn, __shfl_xor(mn, 32));
            if (lane < 16) {
                const uint32_t pk = (uint32_t)__builtin_bit_cast(uint16_t, (__bf16)mx) |
                                    ((uint32_t)__builtin_bit_cast(uint16_t, (__bf16)mn) << 16);
                mm[((size_t)b * NPTS + n) * 64 + ot * 16 + lane] = pk;
            }
        }
    }
    #pragma unroll
    for (int ot = 0; ot < 4; ++ot) {
        sA[ot] += __shfl_xor(sA[ot], 16); sA[ot] += __shfl_xor(sA[ot], 32);
        sQ[ot] += __shfl_xor(sQ[ot], 16); sQ[ot] += __shfl_xor(sQ[ot], 32);
    }
    if (lane < 16) {
        #pragma unroll
        for (int ot = 0; ot < 4; ++ot) {
            red[(wave * 2 + 0) * NCH + ot * 16 + lane] = sA[ot];
            red[(wave * 2 + 1) * NCH + ot * 16 + lane] = sQ[ot];
        }
    }
    __syncthreads();
    if (threadIdx.x < NCH) {
        float S = 0.f, Q = 0.f;
        for (int w = 0; w < 4; ++w) {
            S += red[(w * 2 + 0) * NCH + threadIdx.x];
            Q += red[(w * 2 + 1) * NCH + threadIdx.x];
        }
        atomicAdd(&stats[128 + threadIdx.x], S);
        atomicAdd(&stats[192 + threadIdx.x], Q);
    }
}

// ---------------- K3: finalize BN2 + LReLU (max folded via monotonicity) ----------------
__global__ __launch_bounds__(256) void final_kernel(const uint32_t* __restrict__ mm,
                                                    const float* __restrict__ stats,
                                                    const float* __restrict__ g2,
                                                    const float* __restrict__ be2,
                                                    float* __restrict__ out) {
    const int b  = blockIdx.x >> 7;
    const int n0 = (blockIdx.x & 127) * 32;
    __shared__ uint32_t ms[32 * 65];
    const uint32_t* src = mm + ((size_t)b * NPTS + n0) * 64;
    for (int i = threadIdx.x; i < 32 * 64; i += 256)
        ms[(i >> 6) * 65 + (i & 63)] = src[i];
    __syncthreads();
    const int o  = threadIdx.x >> 2;
    const int ns = (threadIdx.x & 3) * 8;
    const float inv = 1.0f / MCNT;
    const float m2 = stats[128 + o] * inv;
    const float v2 = fmaf(-m2, m2, stats[192 + o] * inv);
    const float a2 = g2[o] * rsqrtf(v2 + EPS);
    const float bb2 = fmaf(-m2, a2, be2[o]);
    float* dst = out + ((size_t)b * NCH + o) * NPTS + n0 + ns;
    #pragma unroll
    for (int j = 0; j < 8; ++j) {
        const uint32_t u = ms[(ns + j) * 65 + o];
        const float mx = __uint_as_float(u << 16);
        const float mn = __uint_as_float(u & 0xFFFF0000u);
        const float sel = (a2 >= 0.f) ? mx : mn;
        float h = fmaf(a2, sel, bb2);
        h = (h >= 0.f) ? h : SLOPE * h;
        dst[j] = h;
    }
}

extern "C" void kernel_launch(void* const* d_in, const int* in_sizes, int n_in,
                              void* d_out, int out_size, void* d_ws, size_t ws_size,
                              hipStream_t stream) {
    (void)in_sizes; (void)n_in; (void)out_size; (void)ws_size;
    const float* x   = (const float*)d_in[0];
    const float* W1  = (const float*)d_in[1];
    const float* g1  = (const float*)d_in[2];
    const float* be1 = (const float*)d_in[3];
    const float* W2  = (const float*)d_in[4];
    const float* g2  = (const float*)d_in[5];
    const float* be2 = (const float*)d_in[6];
    float* out   = (float*)d_out;
    float* stats = (float*)d_ws;                            // 4 KB page
    int*   idx   = (int*)((char*)d_ws + 4096);              // 4 MB
    uint32_t* mm = (uint32_t*)((char*)d_ws + 4096 + (size_t)NPTS * 8 * KNB * 4); // 8 MB
    hipMemsetAsync(d_ws, 0, 4096, stream);
    knn_kernel<<<dim3(512), dim3(1024), 0, stream>>>(x, W1, idx, stats);
    conv_kernel<<<dim3(1024), dim3(256), 0, stream>>>(x, W1, W2, g1, be1, idx, stats, mm);
    final_kernel<<<dim3(1024), dim3(256), 0, stream>>>(mm, stats, g2, be2, out);
}